// Round 7
// baseline (53.594 us; speedup 1.0000x reference)
//
#include <hip/hip_runtime.h>

#define EPS 1e-8f

// float2 with 4-byte alignment guarantee (F=257 odd makes 8B alignment
// impossible to maintain across t; CDNA global dwordx2 only needs 4B align).
typedef float v2f __attribute__((ext_vector_type(2)));
typedef v2f uv2f __attribute__((aligned(4)));

// ---------------------------------------------------------------------------
// Two-kernel chunked scan, float2-vectorized over feature pairs.
// Pairing: vector-unit vu = (b, fp), fp in [0, NP), NP=(F+1)/2. fp<F/2 handles
// chains f=2fp, 2fp+1 as one float2 stream; the odd-F tail (f=F-1) is scalar.
// Thread (vu, c) owns time-chunk c (length L) of its chain pair.
// k1: zero-carry local scan -> aggregates S[c][bf] (chunks 0..C-2 only).
// k2: Horner-reconstruct exact carry-in from s0 + S[0..c) (arithmetic
//     identical to a sequential middle pass), rescan, normalize, store.
// ---------------------------------------------------------------------------

__device__ __forceinline__ float sigmoidf_(float x) {
    return 1.0f / (1.0f + expf(-x));
}

template <int L>
__global__ __launch_bounds__(256)
void fns7_aggregate(const float* __restrict__ mag,
                    const float* __restrict__ alpha,
                    float* __restrict__ S,   // [C-1][BF]
                    int B, int T, int F, int C1, int NP) {
    const int BF = B * F;
    const int VU = B * NP;
    int g = blockIdx.x * blockDim.x + threadIdx.x;
    if (g >= VU * C1) return;
    const int vu = g % VU;
    const int c  = g / VU;
    const int b  = vu / NP;
    const int fp = vu - b * NP;
    const int f  = 2 * fp;
    const bool pair = (f + 1 < F);

    const float a0 = sigmoidf_(alpha[f]);
    const float o0 = 1.0f - a0;
    const float a1 = pair ? sigmoidf_(alpha[f + 1]) : 0.0f;
    const float o1 = 1.0f - a1;

    const float* p = mag + ((size_t)b * T + (size_t)c * L) * F + f;

    float l0 = 0.0f, l1 = 0.0f;
    if (pair) {
#pragma unroll
        for (int t = 0; t < L; ++t) {
            v2f m = *(const uv2f*)(p + (size_t)t * F);
            l0 = l0 * o0 + (m.x * m.x) * a0;   // exact reference form
            l1 = l1 * o1 + (m.y * m.y) * a1;
        }
    } else {
#pragma unroll
        for (int t = 0; t < L; ++t) {
            float m = p[(size_t)t * F];
            l0 = l0 * o0 + (m * m) * a0;
        }
    }

    float* sp = S + (size_t)c * BF + (size_t)b * F + f;
    if (pair) { v2f v; v.x = l0; v.y = l1; *(uv2f*)sp = v; }
    else      { *sp = l0; }
}

template <int L>
__global__ __launch_bounds__(256)
void fns7_emit(const float* __restrict__ mag,
               const float* __restrict__ s0,
               const float* __restrict__ weights,
               const float* __restrict__ bias,
               const float* __restrict__ alpha,
               const float* __restrict__ S,   // [C-1][BF]
               float* __restrict__ out,
               int B, int T, int F, int C, int NP) {
    const int BF = B * F;
    const int VU = B * NP;
    int g = blockIdx.x * blockDim.x + threadIdx.x;
    if (g >= VU * C) return;
    const int vu = g % VU;
    const int c  = g / VU;
    const int b  = vu / NP;
    const int fp = vu - b * NP;
    const int f  = 2 * fp;
    const bool pair = (f + 1 < F);

    const float a0 = sigmoidf_(alpha[f]);
    const float o0 = 1.0f - a0;
    const float w0 = weights[f];
    const float bi0 = bias[f];
    const float a1 = pair ? sigmoidf_(alpha[f + 1]) : 0.0f;
    const float o1 = 1.0f - a1;
    const float w1 = pair ? weights[f + 1] : 0.0f;
    const float bi1 = pair ? bias[f + 1] : 0.0f;

    // exact carry-in via Horner over preceding chunk aggregates
    const int bf = b * F + f;
    float x0 = s0[bf];
    float x1 = pair ? s0[bf + 1] : 0.0f;
    if (c > 0) {
        float D0 = 1.0f, D1 = 1.0f;          // (1-a)^L via product
#pragma unroll
        for (int i = 0; i < L; ++i) { D0 *= o0; D1 *= o1; }
        for (int j = 0; j < c; ++j) {
            const float* sp = S + (size_t)j * BF + bf;
            if (pair) { v2f v = *(const uv2f*)sp; x0 = x0 * D0 + v.x; x1 = x1 * D1 + v.y; }
            else      { x0 = x0 * D0 + *sp; }
        }
    }

    const float* p = mag + ((size_t)b * T + (size_t)c * L) * F + f;
    float*       o = out + ((size_t)b * T + (size_t)c * L) * F + f;

    if (pair) {
#pragma unroll
        for (int t = 0; t < L; ++t) {
            v2f m = *(const uv2f*)(p + (size_t)t * F);
            x0 = x0 * o0 + (m.x * m.x) * a0;
            x1 = x1 * o1 + (m.y * m.y) * a1;
            v2f r;
            r.x = m.x * __builtin_amdgcn_rcpf(sqrtf(x0) + EPS) * w0 + bi0;
            r.y = m.y * __builtin_amdgcn_rcpf(sqrtf(x1) + EPS) * w1 + bi1;
            *(uv2f*)(o + (size_t)t * F) = r;
        }
    } else {
#pragma unroll
        for (int t = 0; t < L; ++t) {
            float m = p[(size_t)t * F];
            x0 = x0 * o0 + (m * m) * a0;
            o[(size_t)t * F] = m * __builtin_amdgcn_rcpf(sqrtf(x0) + EPS) * w0 + bi0;
        }
    }
}

// ---------------------------------------------------------------------------
// Fallback: one thread per (b,f) chain (general shapes / tiny workspace).
// ---------------------------------------------------------------------------
__global__ void fns_fallback(const float* __restrict__ mag,
                             const float* __restrict__ s0,
                             const float* __restrict__ weights,
                             const float* __restrict__ bias,
                             const float* __restrict__ alpha,
                             float* __restrict__ out,
                             int B, int T, int F) {
    int bf = blockIdx.x * blockDim.x + threadIdx.x;
    int BF = B * F;
    if (bf >= BF) return;
    int b = bf / F;
    int f = bf - b * F;

    float a  = 1.0f / (1.0f + expf(-alpha[f]));
    float w  = weights[f];
    float bi = bias[f];

    float carry = s0[bf];
    const float* p = mag + (size_t)b * T * F + f;
    float*       o = out + (size_t)b * T * F + f;

    for (int t = 0; t < T; ++t) {
        float m = p[(size_t)t * F];
        carry = carry * (1.0f - a) + (m * m) * a;
        o[(size_t)t * F] = m / (sqrtf(carry) + EPS) * w + bi;
    }
}

extern "C" void kernel_launch(void* const* d_in, const int* in_sizes, int n_in,
                              void* d_out, int out_size, void* d_ws, size_t ws_size,
                              hipStream_t stream) {
    const float* mag     = (const float*)d_in[0];
    const float* s0      = (const float*)d_in[1];
    const float* weights = (const float*)d_in[2];
    const float* bias    = (const float*)d_in[3];
    const float* alpha   = (const float*)d_in[4];
    float* out = (float*)d_out;

    int F  = in_sizes[4];          // alpha is [1, F]
    int BF = in_sizes[1];          // s is [B, F]
    int B  = BF / F;
    int T  = in_sizes[0] / BF;     // mag is [B, T, F]

    constexpr int L = 50;          // compile-time chunk length (full unroll)
    if (T % L == 0) {
        int C  = T / L;            // 20 for T=1000
        int C1 = C - 1;
        int NP = (F + 1) / 2;      // 129 vector-units per b
        size_t need = (size_t)C1 * BF * sizeof(float);
        if (C1 >= 1 && ws_size >= need) {
            float* S = (float*)d_ws;
            int VU = B * NP;                       // 8256
            int n1 = VU * C1;                      // 156,864
            int n2 = VU * C;                       // 165,120
            fns7_aggregate<L><<<(n1 + 255) / 256, 256, 0, stream>>>(
                mag, alpha, S, B, T, F, C1, NP);
            fns7_emit<L><<<(n2 + 255) / 256, 256, 0, stream>>>(
                mag, s0, weights, bias, alpha, S, out, B, T, F, C, NP);
            return;
        }
    }

    int threads = 256;
    int blocks  = (BF + threads - 1) / threads;
    fns_fallback<<<blocks, threads, 0, stream>>>(mag, s0, weights, bias,
                                                 alpha, out, B, T, F);
}